// Round 9
// baseline (184.283 us; speedup 1.0000x reference)
//
#include <hip/hip_runtime.h>

#define N_ROWS 32768
#define DIM    256
#define KCODES 2048
#define CSCALE 4096.0f
#define BROWS  32            // rows per block

typedef __attribute__((ext_vector_type(16))) float f32x16;
typedef __attribute__((ext_vector_type(4)))  unsigned int u32x4;

union frag16 { u32x4 v; long l[2]; };

// pack 16 fp32 -> 16 fp8 e4m3 (4 dwords)
__device__ __forceinline__ uint4 pack16(const float* s) {
    int a = __builtin_amdgcn_cvt_pk_fp8_f32(s[0],  s[1],  0, false);
    a     = __builtin_amdgcn_cvt_pk_fp8_f32(s[2],  s[3],  a, true);
    int b = __builtin_amdgcn_cvt_pk_fp8_f32(s[4],  s[5],  0, false);
    b     = __builtin_amdgcn_cvt_pk_fp8_f32(s[6],  s[7],  b, true);
    int c = __builtin_amdgcn_cvt_pk_fp8_f32(s[8],  s[9],  0, false);
    c     = __builtin_amdgcn_cvt_pk_fp8_f32(s[10], s[11], c, true);
    int d = __builtin_amdgcn_cvt_pk_fp8_f32(s[12], s[13], 0, false);
    d     = __builtin_amdgcn_cvt_pk_fp8_f32(s[14], s[15], d, true);
    uint4 o; o.x = a; o.y = b; o.z = c; o.w = d;
    return o;
}

// ---------------- prologue 1: half-codenorm + loss init ------------------------
__global__ void prep_h(const float* __restrict__ cb,
                       float* __restrict__ halfcn, float* __restrict__ loss) {
    const int t    = threadIdx.x;            // 256 thr = 4 codes x 64 slots
    const int code = blockIdx.x * 4 + (t >> 6);
    const int s    = t & 63;
    if (blockIdx.x == 0 && t == 0) *loss = 0.0f;
    const int kc = s >> 4, d = (s >> 2) & 3, b4 = (s & 3) * 4;
    const int h = d >> 1, q = d & 1;
    const int k0 = kc * 64 + q * 32 + (b4 >> 3) * 16 + h * 8 + (b4 & 7);
    float4 v = *(const float4*)&cb[(size_t)code * DIM + k0];
    float ssum = v.x * v.x + v.y * v.y + v.z * v.z + v.w * v.w;
    #pragma unroll
    for (int o = 32; o > 0; o >>= 1) ssum += __shfl_down(ssum, o, 64);
    if (s == 0) halfcn[code] = 0.5f * CSCALE * ssum;
}

// ---------------- prologue 2: codebook -> fragment-major fp8 buffer ------------
// cbF region (i=pass*4+kc, w, ct, j): 1 KB = 64 lanes x 16B. Lane L (h=L>>5,
// l32=L&31) holds logical piece d=h*2+j of code (pass*256+w*64+ct*32+l32),
// k-chunk kc. The K-loop's B-loads are then plain coalesced global_load_dwordx4
// straight into registers -- no LDS, no swizzle, no ds_read on the B path.
__global__ void prep_frag(const float* __restrict__ cb, uint4* __restrict__ cbF) {
    const int gid = blockIdx.x * 256 + threadIdx.x;   // [0, 32768)
    const int L   = gid & 63;
    const int r   = gid >> 6;                         // [0, 512)
    const int j   = r & 1;
    const int ct  = (r >> 1) & 1;
    const int w   = (r >> 2) & 3;
    const int i   = r >> 4;                           // [0, 32)
    const int pass = i >> 2, kc = i & 3;
    const int h   = L >> 5, l32 = L & 31;
    const int code = pass * 256 + w * 64 + ct * 32 + l32;
    // logical piece d = h*2 + j  =>  hh = h, q = j
    float buf[16];
    #pragma unroll
    for (int b = 0; b < 4; b++) {
        const int k0 = kc * 64 + j * 32 + (b >> 1) * 16 + h * 8 + (b & 1) * 4;
        float4 v = *(const float4*)&cb[(size_t)code * DIM + k0];
        buf[b * 4 + 0] = v.x * CSCALE; buf[b * 4 + 1] = v.y * CSCALE;
        buf[b * 4 + 2] = v.z * CSCALE; buf[b * 4 + 3] = v.w * CSCALE;
    }
    cbF[gid] = pack16(buf);
}

// ---------------- fused: argmin over all 2048 codes + gather + loss -------------
// B path fully in registers: 3-deep prefetch ring (bfr), 4 coalesced 1KB loads
// per K-step from the fragment-major L2-resident buffer.
// Single-variable change vs measured round-6 kernel: launch_bounds (256,3)->(256,4).
// Live state = 84 arch VGPR + 32 AGPR = 116 <= 128 (4-wave/SIMD budget), so the
// cap is satisfiable WITHOUT spill (round 2's (256,4) failure had ~145 live).
// Grid 1024 = exactly 4 blocks/CU resident: one uniform generation, no straggler
// tail; doubles per-SIMD MFMA issue density and outstanding-load MLP.
__global__ __launch_bounds__(256, 4) void vq_fused(
        const float* __restrict__ x, const float* __restrict__ cb,
        const uint4* __restrict__ cbF, const float* __restrict__ halfcn,
        float* __restrict__ out, float* __restrict__ loss) {
    __shared__ char As[4][2048];      // [kc][32 rows x 64B], 16B-granule XOR swizzle
    __shared__ float hcs[KCODES];     // per-code bias (0.5*CSCALE*||c||^2)
    // epilogue scratch overlays As (A is consumed into registers before the loop)
    struct Tail { float red[BROWS][4]; int idxs[BROWS]; float lred[4]; };
    Tail* tl = (Tail*)As;

    const int t    = threadIdx.x;
    const int lane = t & 63;
    const int w    = t >> 6;
    const int l32  = lane & 31;
    const int h    = lane >> 5;
    const int row0 = blockIdx.x * BROWS;

    // ---- stage A once: fp32 -> fp8 e4m3 pieces, swizzled LDS ----
    {
        const int r   = t >> 3;              // 0..31
        const int kc  = (t >> 1) & 3;
        const int pp  = t & 1;               // piece pair
        const int key = (r >> 1) & 3;
        const float* src = x + (size_t)(row0 + r) * DIM + kc * 64;
        float buf[16];
        #pragma unroll
        for (int pi = 0; pi < 2; pi++) {
            const int p = pp * 2 + pi;
            const int d = p ^ key, hh = d >> 1, qq = d & 1;
            #pragma unroll
            for (int j = 0; j < 4; j++) *(float4*)(buf + j * 4) =
                *(const float4*)(src + qq * 32 + (j >> 1) * 16 + hh * 8 + (j & 1) * 4);
            *(uint4*)(As[kc] + r * 64 + p * 16) = pack16(buf);
        }
        #pragma unroll
        for (int jj = 0; jj < 8; jj++) hcs[jj * 256 + t] = halfcn[jj * 256 + t];
    }

    const int key = (l32 >> 1) & 3;
    const int p0  = (h * 2 + 0) ^ key;
    const int p1  = (h * 2 + 1) ^ key;

    float mp[16];
    #pragma unroll
    for (int r = 0; r < 16; r++) mp[r] = -3.0e38f;

    // B prefetch base: per-wave, per-lane
    const char* bbase = (const char*)cbF + w * 4096 + (size_t)lane * 16;

    // start B prefetch (steps 0..2) BEFORE the barrier: overlaps stage-A
    frag16 bfr[3][4];   // [slot][ct*2+j] — literal-indexed under full unroll
    #pragma unroll
    for (int s = 0; s < 3; s++)
        #pragma unroll
        for (int c = 0; c < 4; c++)
            bfr[s][c].v = *(const u32x4*)(bbase + s * 16384 + c * 1024);

    __syncthreads();                  // As + hcs visible

    // A fragments -> registers (read once; As is dead afterwards)
    frag16 afr[4][2];
    #pragma unroll
    for (int kc = 0; kc < 4; kc++) {
        const char* ab = As[kc];
        const int rbase = l32 * 64;
        afr[kc][0].v = *(const u32x4*)(ab + rbase + p0 * 16);
        afr[kc][1].v = *(const u32x4*)(ab + rbase + p1 * 16);
    }

    #pragma unroll
    for (int pass = 0; pass < 8; ++pass) {
        const float hc0 = hcs[pass * 256 + w * 64 + l32];
        const float hc1 = hcs[pass * 256 + w * 64 + 32 + l32];
        f32x16 acc[2];
        #pragma unroll
        for (int r = 0; r < 16; r++) {
            acc[0][r] = -hc0;
            acc[1][r] = -hc1;
        }

        #pragma unroll
        for (int kc = 0; kc < 4; ++kc) {
            const int i  = pass * 4 + kc;
            const int sl = i % 3;            // literal per unroll

            // current step's fragments (loaded 3 steps ago)
            frag16 cur[4];
            #pragma unroll
            for (int c = 0; c < 4; c++) cur[c] = bfr[sl][c];

            // refill slot with step i+3 (SSA: WAR handled by renaming)
            if (i + 3 < 32) {
                #pragma unroll
                for (int c = 0; c < 4; c++)
                    bfr[sl][c].v = *(const u32x4*)(bbase + (i + 3) * 16384 + c * 1024);
            }

            // 8 MFMAs for step i; compiler inserts precise vmcnt for cur deps
            #pragma unroll
            for (int q = 0; q < 2; q++)
                #pragma unroll
                for (int hf = 0; hf < 2; hf++)
                    #pragma unroll
                    for (int ct = 0; ct < 2; ct++)
                        acc[ct] = __builtin_amdgcn_mfma_f32_32x32x16_fp8_fp8(
                            afr[kc][q].l[hf], cur[ct * 2 + q].l[hf],
                            acc[ct], 0, 0, 0);
        }

        // fold pass into running max (pack 11-bit code id into low mantissa bits)
        #pragma unroll
        for (int ct = 0; ct < 2; ct++) {
            const unsigned code = (unsigned)(pass * 256 + w * 64 + ct * 32 + l32);
            #pragma unroll
            for (int r = 0; r < 16; r++) {
                unsigned u = (__float_as_uint(acc[ct][r]) & 0xFFFFF800u) | code;
                mp[r] = fmaxf(mp[r], __uint_as_float(u));
            }
        }
    }

    // ---- cross-lane argmax over the 32 lanes sharing each output row ----
    #pragma unroll
    for (int m = 1; m <= 16; m <<= 1)
        #pragma unroll
        for (int r = 0; r < 16; r++)
            mp[r] = fmaxf(mp[r], __shfl_xor(mp[r], m, 64));

    __syncthreads();                  // everyone past As reads (overlay safe)

    if (l32 == 0) {
        #pragma unroll
        for (int r = 0; r < 16; r++) {
            const int row = (r & 3) + 8 * (r >> 2) + 4 * h;   // 0..31
            tl->red[row][w] = mp[r];
        }
    }
    __syncthreads();
    if (t < BROWS) {
        float b0 = fmaxf(fmaxf(tl->red[t][0], tl->red[t][1]),
                         fmaxf(tl->red[t][2], tl->red[t][3]));
        tl->idxs[t] = (int)(__float_as_uint(b0) & 2047u);
    }
    __syncthreads();

    // ---- fused gather (fp32 codebook) + loss partial ----
    float lsum = 0.0f;
    #pragma unroll 4
    for (int r = 0; r < BROWS; r++) {
        const int code = tl->idxs[r];
        const float c  = cb[(size_t)code * DIM + t];
        const float xv = x[(size_t)(row0 + r) * DIM + t];
        out[(size_t)(row0 + r) * DIM + t] = c;
        const float d = xv - c;
        lsum += d * d;
    }
    #pragma unroll
    for (int o = 32; o > 0; o >>= 1) lsum += __shfl_down(lsum, o, 64);
    if (lane == 0) tl->lred[w] = lsum;
    __syncthreads();
    if (t == 0) {
        const float scale = 1.25f / (float)((size_t)N_ROWS * DIM);  // (beta+1)/(N*D)
        atomicAdd(loss, (tl->lred[0] + tl->lred[1] + tl->lred[2] + tl->lred[3]) * scale);
    }
}

extern "C" void kernel_launch(void* const* d_in, const int* in_sizes, int n_in,
                              void* d_out, int out_size, void* d_ws, size_t ws_size,
                              hipStream_t stream) {
    const float* x  = (const float*)d_in[0];
    const float* cb = (const float*)d_in[1];
    float* out  = (float*)d_out;
    float* loss = out + (size_t)N_ROWS * DIM;

    char* ws = (char*)d_ws;
    uint4* cbF    = (uint4*)ws;                                    // 512 KB
    float* halfcn = (float*)(ws + (size_t)KCODES * 256);           // 8 KB

    prep_h   <<<KCODES / 4, 256, 0, stream>>>(cb, halfcn, loss);
    prep_frag<<<128,        256, 0, stream>>>(cb, cbF);
    vq_fused <<<N_ROWS / BROWS, 256, 0, stream>>>(x, cb, cbF, halfcn, out, loss);
}

// Round 10
// 122.270 us; speedup vs baseline: 1.5072x; 1.5072x over previous
//
#include <hip/hip_runtime.h>

#define N_ROWS 32768
#define DIM    256
#define KCODES 2048
#define CSCALE 4096.0f
#define BROWS  64            // rows per block (wave = row-group x code-group)

typedef __attribute__((ext_vector_type(16))) float f32x16;
typedef __attribute__((ext_vector_type(4)))  unsigned int u32x4;

union frag16 { u32x4 v; long l[2]; };

// pack 16 fp32 -> 16 fp8 e4m3 (4 dwords)
__device__ __forceinline__ uint4 pack16(const float* s) {
    int a = __builtin_amdgcn_cvt_pk_fp8_f32(s[0],  s[1],  0, false);
    a     = __builtin_amdgcn_cvt_pk_fp8_f32(s[2],  s[3],  a, true);
    int b = __builtin_amdgcn_cvt_pk_fp8_f32(s[4],  s[5],  0, false);
    b     = __builtin_amdgcn_cvt_pk_fp8_f32(s[6],  s[7],  b, true);
    int c = __builtin_amdgcn_cvt_pk_fp8_f32(s[8],  s[9],  0, false);
    c     = __builtin_amdgcn_cvt_pk_fp8_f32(s[10], s[11], c, true);
    int d = __builtin_amdgcn_cvt_pk_fp8_f32(s[12], s[13], 0, false);
    d     = __builtin_amdgcn_cvt_pk_fp8_f32(s[14], s[15], d, true);
    uint4 o; o.x = a; o.y = b; o.z = c; o.w = d;
    return o;
}

// ---------------- prologue 1: half-codenorm + loss init ------------------------
__global__ void prep_h(const float* __restrict__ cb,
                       float* __restrict__ halfcn, float* __restrict__ loss) {
    const int t    = threadIdx.x;            // 256 thr = 4 codes x 64 slots
    const int code = blockIdx.x * 4 + (t >> 6);
    const int s    = t & 63;
    if (blockIdx.x == 0 && t == 0) *loss = 0.0f;
    const int kc = s >> 4, d = (s >> 2) & 3, b4 = (s & 3) * 4;
    const int h = d >> 1, q = d & 1;
    const int k0 = kc * 64 + q * 32 + (b4 >> 3) * 16 + h * 8 + (b4 & 7);
    float4 v = *(const float4*)&cb[(size_t)code * DIM + k0];
    float ssum = v.x * v.x + v.y * v.y + v.z * v.z + v.w * v.w;
    #pragma unroll
    for (int o = 32; o > 0; o >>= 1) ssum += __shfl_down(ssum, o, 64);
    if (s == 0) halfcn[code] = 0.5f * CSCALE * ssum;
}

// ---------------- prologue 2: codebook -> fragment-major fp8 buffer ------------
// NEW layout for the row/code wave-split: region (i = p*4+kc in [0,64), cg, ct, j)
// = 1 KB of 64 lanes x 16B. Byte offset = i*8192 + cg*4096 + (ct*2+j)*1024 + L*16.
// Code = p*128 + cg*64 + ct*32 + l32 (16 passes of 128 codes). Wave w uses
// cg = w&1; waves (0,2) and (1,3) stream IDENTICAL lines -> L1 reuse.
__global__ void prep_frag(const float* __restrict__ cb, uint4* __restrict__ cbF) {
    const int gid  = blockIdx.x * 256 + threadIdx.x;  // [0, 32768)
    const int L    = gid & 63;
    const int rest = gid >> 6;                        // [0, 512)
    const int j    = rest & 1;
    const int ct   = (rest >> 1) & 1;
    const int cg   = (rest >> 2) & 1;
    const int i    = rest >> 3;                       // [0, 64)
    const int p    = i >> 2, kc = i & 3;
    const int h    = L >> 5, l32 = L & 31;
    const int code = p * 128 + cg * 64 + ct * 32 + l32;
    float buf[16];
    #pragma unroll
    for (int b = 0; b < 4; b++) {
        const int k0 = kc * 64 + j * 32 + (b >> 1) * 16 + h * 8 + (b & 1) * 4;
        float4 v = *(const float4*)&cb[(size_t)code * DIM + k0];
        buf[b * 4 + 0] = v.x * CSCALE; buf[b * 4 + 1] = v.y * CSCALE;
        buf[b * 4 + 2] = v.z * CSCALE; buf[b * 4 + 3] = v.w * CSCALE;
    }
    cbF[gid] = pack16(buf);
}

// ---------------- fused: argmin over all 2048 codes + gather + loss -------------
// Round-6 K-loop kernel (measured 50.2us, VGPR 84, no spill) with ONE structural
// change: BROWS 32->64, wave = (row-group w>>1, code-group w&1). Halves blocks
// (grid 512) => per-CU lifetime codebook traffic 2MB -> 1MB, and wave-pairs
// sharing a code-group hit L1 on each other's lines. Inner loop, ring-3 register
// B-path, register footprint, and (256,3) cap are unchanged from the measured
// round-6 kernel.
__global__ __launch_bounds__(256, 3) void vq_fused(
        const float* __restrict__ x, const float* __restrict__ cb,
        const uint4* __restrict__ cbF, const float* __restrict__ halfcn,
        float* __restrict__ out, float* __restrict__ loss) {
    __shared__ char As[4][4096];      // [kc][64 rows x 64B], 16B-granule XOR swizzle
    __shared__ float hcs[KCODES];     // per-code bias (0.5*CSCALE*||c||^2)
    // epilogue scratch overlays As (A is consumed into registers before the loop)
    struct Tail { float red[BROWS][2]; int idxs[BROWS]; float lred[4]; };
    Tail* tl = (Tail*)As;

    const int t    = threadIdx.x;
    const int lane = t & 63;
    const int w    = t >> 6;
    const int l32  = lane & 31;
    const int h    = lane >> 5;
    const int row0 = blockIdx.x * BROWS;
    const int wrow = (w >> 1) * 32;   // wave's row-group base (0 or 32)
    const int cg   = w & 1;           // wave's code-group

    // ---- stage A once: fp32 -> fp8 e4m3 pieces, swizzled LDS (64 rows) ----
    {
        const int r   = t >> 2;              // 0..63
        const int kc  = t & 3;
        const int key = (r >> 1) & 3;
        const float* src = x + (size_t)(row0 + r) * DIM + kc * 64;
        float buf[16];
        #pragma unroll
        for (int p = 0; p < 4; p++) {
            const int d = p ^ key, hh = d >> 1, qq = d & 1;
            #pragma unroll
            for (int j = 0; j < 4; j++) *(float4*)(buf + j * 4) =
                *(const float4*)(src + qq * 32 + (j >> 1) * 16 + hh * 8 + (j & 1) * 4);
            *(uint4*)(As[kc] + r * 64 + p * 16) = pack16(buf);
        }
        #pragma unroll
        for (int jj = 0; jj < 8; jj++) hcs[jj * 256 + t] = halfcn[jj * 256 + t];
    }

    const int key = (l32 >> 1) & 3;   // row wrow+l32: key invariant (wrow % 32 == 0)
    const int p0  = (h * 2 + 0) ^ key;
    const int p1  = (h * 2 + 1) ^ key;

    float mp[16];
    #pragma unroll
    for (int r = 0; r < 16; r++) mp[r] = -3.0e38f;

    // B prefetch base: per-code-group, per-lane
    const char* bbase = (const char*)cbF + cg * 4096 + (size_t)lane * 16;

    // start B prefetch (steps 0..2) BEFORE the barrier: overlaps stage-A
    frag16 bfr[3][4];   // [slot][ct*2+j] — literal-indexed under full unroll
    #pragma unroll
    for (int s = 0; s < 3; s++)
        #pragma unroll
        for (int c = 0; c < 4; c++)
            bfr[s][c].v = *(const u32x4*)(bbase + s * 8192 + c * 1024);

    __syncthreads();                  // As + hcs visible

    // A fragments -> registers (read once; As is dead afterwards)
    frag16 afr[4][2];
    #pragma unroll
    for (int kc = 0; kc < 4; kc++) {
        const char* ab = As[kc];
        const int rbase = (wrow + l32) * 64;
        afr[kc][0].v = *(const u32x4*)(ab + rbase + p0 * 16);
        afr[kc][1].v = *(const u32x4*)(ab + rbase + p1 * 16);
    }

    #pragma unroll
    for (int pass = 0; pass < 16; ++pass) {
        const float hc0 = hcs[pass * 128 + cg * 64 + l32];
        const float hc1 = hcs[pass * 128 + cg * 64 + 32 + l32];
        f32x16 acc[2];
        #pragma unroll
        for (int r = 0; r < 16; r++) {
            acc[0][r] = -hc0;
            acc[1][r] = -hc1;
        }

        #pragma unroll
        for (int kc = 0; kc < 4; ++kc) {
            const int i  = pass * 4 + kc;    // [0, 64)
            const int sl = i % 3;            // literal per unroll

            // current step's fragments (loaded 3 steps ago)
            frag16 cur[4];
            #pragma unroll
            for (int c = 0; c < 4; c++) cur[c] = bfr[sl][c];

            // refill slot with step i+3 (SSA: WAR handled by renaming)
            if (i + 3 < 64) {
                #pragma unroll
                for (int c = 0; c < 4; c++)
                    bfr[sl][c].v = *(const u32x4*)(bbase + (i + 3) * 8192 + c * 1024);
            }

            // 8 MFMAs for step i; compiler inserts precise vmcnt for cur deps
            #pragma unroll
            for (int q = 0; q < 2; q++)
                #pragma unroll
                for (int hf = 0; hf < 2; hf++)
                    #pragma unroll
                    for (int ct = 0; ct < 2; ct++)
                        acc[ct] = __builtin_amdgcn_mfma_f32_32x32x16_fp8_fp8(
                            afr[kc][q].l[hf], cur[ct * 2 + q].l[hf],
                            acc[ct], 0, 0, 0);
        }

        // fold pass into running max (pack 11-bit code id into low mantissa bits)
        #pragma unroll
        for (int ct = 0; ct < 2; ct++) {
            const unsigned code = (unsigned)(pass * 128 + cg * 64 + ct * 32 + l32);
            #pragma unroll
            for (int r = 0; r < 16; r++) {
                unsigned u = (__float_as_uint(acc[ct][r]) & 0xFFFFF800u) | code;
                mp[r] = fmaxf(mp[r], __uint_as_float(u));
            }
        }
    }

    // ---- cross-lane argmax over the 32 lanes sharing each output row ----
    #pragma unroll
    for (int m = 1; m <= 16; m <<= 1)
        #pragma unroll
        for (int r = 0; r < 16; r++)
            mp[r] = fmaxf(mp[r], __shfl_xor(mp[r], m, 64));

    __syncthreads();                  // everyone past As reads (overlay safe)

    if (l32 == 0) {
        #pragma unroll
        for (int r = 0; r < 16; r++) {
            const int row = wrow + (r & 3) + 8 * (r >> 2) + 4 * h;   // 0..63
            tl->red[row][cg] = mp[r];
        }
    }
    __syncthreads();
    if (t < BROWS) {
        float b0 = fmaxf(tl->red[t][0], tl->red[t][1]);
        tl->idxs[t] = (int)(__float_as_uint(b0) & 2047u);
    }
    __syncthreads();

    // ---- fused gather (fp32 codebook) + loss partial ----
    float lsum = 0.0f;
    #pragma unroll 4
    for (int r = 0; r < BROWS; r++) {
        const int code = tl->idxs[r];
        const float c  = cb[(size_t)code * DIM + t];
        const float xv = x[(size_t)(row0 + r) * DIM + t];
        out[(size_t)(row0 + r) * DIM + t] = c;
        const float d = xv - c;
        lsum += d * d;
    }
    #pragma unroll
    for (int o = 32; o > 0; o >>= 1) lsum += __shfl_down(lsum, o, 64);
    if (lane == 0) tl->lred[w] = lsum;
    __syncthreads();
    if (t == 0) {
        const float scale = 1.25f / (float)((size_t)N_ROWS * DIM);  // (beta+1)/(N*D)
        atomicAdd(loss, (tl->lred[0] + tl->lred[1] + tl->lred[2] + tl->lred[3]) * scale);
    }
}

extern "C" void kernel_launch(void* const* d_in, const int* in_sizes, int n_in,
                              void* d_out, int out_size, void* d_ws, size_t ws_size,
                              hipStream_t stream) {
    const float* x  = (const float*)d_in[0];
    const float* cb = (const float*)d_in[1];
    float* out  = (float*)d_out;
    float* loss = out + (size_t)N_ROWS * DIM;

    char* ws = (char*)d_ws;
    uint4* cbF    = (uint4*)ws;                                    // 512 KB
    float* halfcn = (float*)(ws + (size_t)KCODES * 256);           // 8 KB

    prep_h   <<<KCODES / 4, 256, 0, stream>>>(cb, halfcn, loss);
    prep_frag<<<128,        256, 0, stream>>>(cb, cbF);
    vq_fused <<<N_ROWS / BROWS, 256, 0, stream>>>(x, cb, cbF, halfcn, out, loss);
}